// Round 3
// baseline (314.575 us; speedup 1.0000x reference)
//
#include <hip/hip_runtime.h>
#include <hip/hip_bf16.h>
#include <stdint.h>
#include <stddef.h>

// Problem constants
#define B_ 32
#define N_ 1024
#define C_ 768
#define H_ 12
#define D_ 64
#define M_ (B_*N_)     // 32768 rows
#define TC_ (3*C_)     // 2304 qkv cols

typedef __bf16 bf16_t;
typedef __attribute__((ext_vector_type(8))) __bf16 bf16x8;
typedef __attribute__((ext_vector_type(4))) __bf16 bf16x4;
typedef __attribute__((ext_vector_type(4))) float  f32x4;
typedef __attribute__((ext_vector_type(16))) float f32x16;

#define MFMA16(a,b,c) __builtin_amdgcn_mfma_f32_16x16x32_bf16(a,b,c,0,0,0)
#define MFMA32(a,b,c) __builtin_amdgcn_mfma_f32_32x32x16_bf16(a,b,c,0,0,0)

__device__ __forceinline__ void lds_load16(const void* g, void* l) {
  __builtin_amdgcn_global_load_lds(
      (const __attribute__((address_space(1))) void*)g,
      (__attribute__((address_space(3))) void*)l, 16, 0, 0);
}

// ---------------------------------------------------------------- converts
__global__ void cvt_bf16(const float* __restrict__ in, bf16_t* __restrict__ out, int n) {
  int i = (blockIdx.x * 256 + threadIdx.x) * 8;
  if (i >= n) return;
  const float4 a = *(const float4*)(in + i);
  const float4 b = *(const float4*)(in + i + 4);
  bf16x8 r;
  r[0]=(bf16_t)a.x; r[1]=(bf16_t)a.y; r[2]=(bf16_t)a.z; r[3]=(bf16_t)a.w;
  r[4]=(bf16_t)b.x; r[5]=(bf16_t)b.y; r[6]=(bf16_t)b.z; r[7]=(bf16_t)b.w;
  *(bf16x8*)(out + i) = r;
}

// out[c][r] = bf16(in[r][c]); grid (Cc/32, R/32), 256 threads
__global__ void transpose_cvt(const float* __restrict__ in, bf16_t* __restrict__ out,
                              int R, int Cc) {
  __shared__ float t[32][33];
  const int c0 = blockIdx.x * 32, r0 = blockIdx.y * 32;
  const int tx = threadIdx.x & 31, ty = threadIdx.x >> 5;  // ty 0..7
  #pragma unroll
  for (int k = 0; k < 4; ++k)
    t[ty + k*8][tx] = in[(size_t)(r0 + ty + k*8)*Cc + c0 + tx];
  __syncthreads();
  #pragma unroll
  for (int k = 0; k < 4; ++k)
    out[(size_t)(c0 + ty + k*8)*R + r0 + tx] = (bf16_t)t[tx][ty + k*8];
}

// ---------------------------------------------------------------- GEMM 128x128, 32x32x16 MFMA
// LDS tile [128][32] bf16 per operand, rows of 64 B = 4 chunks of 16 B.
// Chunk-swizzle (involution): physical chunk = logical chunk ^ ((row>>1)&3).
// Stage: linear LDS dest (global_load_lds), source global address pre-swizzled.
// MODE 1: qkv projection; scatter epilogue (q -> (b,h,n,d); k,v -> (b,h,d,n))
// MODE 3: out projection; A = qh gathered as (b*1024+n, h*64+d); fp32 out + bias;
//         BT has per-batch stride bt_bstride.
template<int MODE>
__global__ __launch_bounds__(256, 2)
void gemm_bt(const bf16_t* __restrict__ A, const bf16_t* __restrict__ BT,
             const float* __restrict__ bias, float* __restrict__ Cout,
             bf16_t* __restrict__ qh,
             bf16_t* __restrict__ kthi, bf16_t* __restrict__ vthi,
             int K, int nbx, size_t bt_bstride)
{
  // union: staging buffers (16 KB) reused as 128x136 bf16 epilogue tile (34 KB)
  __shared__ __align__(16) char smem[34816];
  bf16_t* As   = (bf16_t*)smem;            // [128][32]
  bf16_t* Bs   = (bf16_t*)(smem + 8192);   // [128][32]
  bf16_t* tile = (bf16_t*)smem;            // [128 cols][pitch 136 rows]

  const int nwg = gridDim.x;
  const int cpx = nwg >> 3;                       // nwg % 8 == 0
  const int bid = blockIdx.x;
  const int swz = (bid & 7) * cpx + (bid >> 3);   // bijective XCD chunking
  const int bx  = swz % nbx;
  const int by  = swz / nbx;

  const int tid  = threadIdx.x;
  const int wave = tid >> 6;
  const int lane = tid & 63;
  const int rowBase = by * 128;
  const int colBase = bx * 128;
  const int wr = (wave >> 1) * 64;
  const int wc = (wave &  1) * 64;
  const int l31 = lane & 31;        // 32x32 frag row/col
  const int lhi = lane >> 5;        // 32x32 frag k-group
  const int xr  = (lane >> 1) & 3;  // read-side chunk XOR = (fragrow>>1)&3
  const int r0t = tid >> 2;         // staging: LDS row (per 64-row half-tile)
  const int c0s = (((tid & 3) ^ ((tid >> 3) & 3)) << 3);  // swizzled source elem offset

  const bf16_t* Bp = BT + (MODE == 3 ? (size_t)(rowBase >> 10) * bt_bstride : 0)
                        + (size_t)(colBase + r0t) * K + c0s;
  const bf16_t* Ap;
  if (MODE == 3) {
    const int gr = rowBase + r0t;
    Ap = A + (size_t)(gr >> 10) * (H_ * N_ * D_) + (size_t)(gr & (N_ - 1)) * D_ + c0s;
  } else {
    Ap = A + (size_t)(rowBase + r0t) * K + c0s;
  }

  f32x16 acc[2][2];
  #pragma unroll
  for (int m = 0; m < 2; ++m)
    #pragma unroll
    for (int n = 0; n < 2; ++n)
      #pragma unroll
      for (int j = 0; j < 16; ++j) acc[m][n][j] = 0.f;

  for (int k0 = 0; k0 < K; k0 += 32) {
    const bf16_t* a0;
    size_t a_half;   // offset of rows +64
    if (MODE == 3) { a0 = Ap + (size_t)(k0 >> 6) * (N_ * D_) + (k0 & 63); a_half = (size_t)64 * D_; }
    else           { a0 = Ap + k0;                                        a_half = (size_t)64 * K;  }
    lds_load16(a0,              &As[wave * 512]);
    lds_load16(a0 + a_half,     &As[2048 + wave * 512]);
    lds_load16(Bp + k0,                  &Bs[wave * 512]);
    lds_load16(Bp + (size_t)64 * K + k0, &Bs[2048 + wave * 512]);
    __syncthreads();
    bf16x8 af[2][2], bfv[2][2];
    #pragma unroll
    for (int m = 0; m < 2; ++m)
      #pragma unroll
      for (int kk = 0; kk < 2; ++kk)
        af[m][kk] = *(const bf16x8*)&As[(wr + m*32 + l31)*32 + (((2*kk + lhi) ^ xr) << 3)];
    #pragma unroll
    for (int n = 0; n < 2; ++n)
      #pragma unroll
      for (int kk = 0; kk < 2; ++kk)
        bfv[n][kk] = *(const bf16x8*)&Bs[(wc + n*32 + l31)*32 + (((2*kk + lhi) ^ xr) << 3)];
    #pragma unroll
    for (int m = 0; m < 2; ++m)
      #pragma unroll
      for (int n = 0; n < 2; ++n)
        #pragma unroll
        for (int kk = 0; kk < 2; ++kk)
          acc[m][n] = MFMA32(af[m][kk], bfv[n][kk], acc[m][n]);
    __syncthreads();
  }

  // C/D layout (32x32): col = lane&31, row = (reg&3) + 8*(reg>>2) + 4*(lane>>5)
  if (MODE == 3) {
    #pragma unroll
    for (int n = 0; n < 2; ++n) {
      const int gc = colBase + wc + n*32 + l31;
      const float bb = bias[gc];
      #pragma unroll
      for (int m = 0; m < 2; ++m)
        #pragma unroll
        for (int g = 0; g < 4; ++g) {
          const int gr = rowBase + wr + m*32 + g*8 + lhi*4;
          #pragma unroll
          for (int j = 0; j < 4; ++j)
            Cout[(size_t)(gr + j)*C_ + gc] = acc[m][n][4*g + j] + bb;
        }
    }
  } else {
    // ---- stage fragments (bias added, bf16) into transposed LDS tile ----
    #pragma unroll
    for (int n = 0; n < 2; ++n) {
      const int c  = wc + n*32 + l31;
      const float bb = bias[colBase + c];
      #pragma unroll
      for (int m = 0; m < 2; ++m)
        #pragma unroll
        for (int g = 0; g < 4; ++g) {
          const int r0 = wr + m*32 + g*8 + lhi*4;
          bf16x4 hv;
          hv[0]=(bf16_t)(acc[m][n][4*g+0]+bb); hv[1]=(bf16_t)(acc[m][n][4*g+1]+bb);
          hv[2]=(bf16_t)(acc[m][n][4*g+2]+bb); hv[3]=(bf16_t)(acc[m][n][4*g+3]+bb);
          *(bf16x4*)&tile[c*136 + r0] = hv;
        }
    }
    __syncthreads();
    const int s   = colBase / C_;          // 0=q 1=k 2=v (uniform per block)
    const int b   = rowBase >> 10;
    const int nn0 = rowBase & (N_ - 1);
    if (s == 0) {
      // q: row-major (b,h,n,d). thread t: row r=t>>1, head-half ch=t&1.
      const int r  = tid >> 1, ch = tid & 1;
      const int h  = (colBase >> 6) + ch;
      bf16_t* dst = qh + (((size_t)b*H_ + h)*N_ + nn0 + r)*D_;
      #pragma unroll
      for (int i0 = 0; i0 < 64; i0 += 8) {
        bf16x8 vv;
        #pragma unroll
        for (int i = 0; i < 8; ++i) vv[i] = tile[(ch*64 + i0 + i)*136 + r];
        *(bf16x8*)&dst[i0] = vv;
      }
    } else {
      // k/v: transposed (b,h,d,n). thread t: col c=t>>1, row-half rh=t&1.
      const int c  = tid >> 1, rh = tid & 1;
      const int rem = colBase + c - s*C_;
      const int h = rem >> 6, d = rem & 63;
      bf16_t* dst = (s == 1 ? kthi : vthi)
                    + (((size_t)b*H_ + h)*D_ + d)*N_ + nn0 + rh*64;
      #pragma unroll
      for (int i0 = 0; i0 < 64; i0 += 8)
        *(bf16x8*)&dst[i0] = *(const bf16x8*)&tile[c*136 + rh*64 + i0];
    }
  }
}

// ---------------------------------------------------------------- stage 2: logits + softmax
// attnT[bh][e][d] = P[d][e], P = softmax_e( sum_n kt[d][n]*vt[e][n] / 8 )
__global__ __launch_bounds__(256, 2)
void attn_softmax_k(const bf16_t* __restrict__ kthi, const bf16_t* __restrict__ vthi,
                    bf16_t* __restrict__ attnT)
{
  __shared__ float tile[64][65];
  __shared__ float invs[64];
  const int bh = blockIdx.x;
  const int tid = threadIdx.x, wave = tid >> 6, lane = tid & 63;
  const int fr = lane & 15, fo = (lane >> 4) * 8;
  const size_t base = (size_t)bh * D_ * N_;
  f32x4 acc[4][4] = {{0.f,0.f,0.f,0.f}};
  const int k0lo = wave * 256;   // split-K across 4 waves
  #pragma unroll 1
  for (int k0 = k0lo; k0 < k0lo + 256; k0 += 32) {
    bf16x8 ah[4], bhv[4];
    #pragma unroll
    for (int m = 0; m < 4; ++m)
      ah[m] = *(const bf16x8*)&kthi[base + (size_t)(m*16 + fr)*N_ + k0 + fo];
    #pragma unroll
    for (int n = 0; n < 4; ++n)
      bhv[n] = *(const bf16x8*)&vthi[base + (size_t)(n*16 + fr)*N_ + k0 + fo];
    #pragma unroll
    for (int m = 0; m < 4; ++m)
      #pragma unroll
      for (int n = 0; n < 4; ++n)
        acc[m][n] = MFMA16(ah[m], bhv[n], acc[m][n]);
  }
  // cross-wave reduce into LDS
  for (int w = 0; w < 4; ++w) {
    if (wave == w) {
      #pragma unroll
      for (int m = 0; m < 4; ++m)
        #pragma unroll
        for (int n = 0; n < 4; ++n) {
          const int row = m*16 + ((lane >> 4) << 2);
          const int col = n*16 + fr;
          #pragma unroll
          for (int j = 0; j < 4; ++j) {
            if (w == 0) tile[row+j][col]  = acc[m][n][j];
            else        tile[row+j][col] += acc[m][n][j];
          }
        }
    }
    __syncthreads();
  }
  // row softmax (scale 1/8), one thread per row d
  if (tid < 64) {
    float mx = -3.0e38f;
    #pragma unroll
    for (int c = 0; c < 64; ++c) mx = fmaxf(mx, tile[tid][c]);
    mx *= 0.125f;
    float ssum = 0.f;
    #pragma unroll
    for (int c = 0; c < 64; ++c) {
      const float ev = __expf(tile[tid][c]*0.125f - mx);
      tile[tid][c] = ev;
      ssum += ev;
    }
    invs[tid] = 1.0f / ssum;
  }
  __syncthreads();
  // transposed write: thread e writes attnT[e][0..63] contiguous
  if (tid < 64) {
    bf16_t* ao = attnT + (size_t)bh * D_ * D_ + tid * D_;
    #pragma unroll
    for (int d0 = 0; d0 < 64; d0 += 8) {
      bf16x8 vv;
      #pragma unroll
      for (int i = 0; i < 8; ++i) vv[i] = (bf16_t)(tile[d0+i][tid] * invs[d0+i]);
      *(bf16x8*)&ao[d0] = vv;
    }
  }
}

// ---------------------------------------------------------------- stage 3: W' compose
// w2t[b][j][h*64+e] = sum_d woutT[j][h*64+d] * attnT[bh][e][d]
// grid (6, B*H), 256 threads (4 waves x 32 j-rows each)
__global__ __launch_bounds__(256, 2)
void compose_w2(const bf16_t* __restrict__ woutT, const bf16_t* __restrict__ attnT,
                bf16_t* __restrict__ w2t)
{
  const int jb = blockIdx.x;
  const int bh = blockIdx.y;
  const int b = bh / H_, h = bh - b*H_;
  const int tid = threadIdx.x, wave = tid >> 6, lane = tid & 63;
  const int fr = lane & 15, fo = (lane >> 4) * 8;
  const bf16_t* at = attnT + (size_t)bh * D_ * D_;
  f32x4 acc[2][4] = {{0.f,0.f,0.f,0.f}};
  #pragma unroll
  for (int kk = 0; kk < 2; ++kk) {
    bf16x8 af[2], bfv[4];
    #pragma unroll
    for (int m = 0; m < 2; ++m)
      af[m] = *(const bf16x8*)&woutT[(size_t)(jb*128 + wave*32 + m*16 + fr)*C_ + h*64 + kk*32 + fo];
    #pragma unroll
    for (int n = 0; n < 4; ++n)
      bfv[n] = *(const bf16x8*)&at[(n*16 + fr)*64 + kk*32 + fo];
    #pragma unroll
    for (int m = 0; m < 2; ++m)
      #pragma unroll
      for (int n = 0; n < 4; ++n)
        acc[m][n] = MFMA16(af[m], bfv[n], acc[m][n]);
  }
  bf16_t* wb = w2t + (size_t)b * C_ * C_;
  #pragma unroll
  for (int m = 0; m < 2; ++m) {
    const int j = jb*128 + wave*32 + m*16 + ((lane >> 4) << 2);
    #pragma unroll
    for (int n = 0; n < 4; ++n) {
      const int e = n*16 + fr;
      #pragma unroll
      for (int jj = 0; jj < 4; ++jj)
        wb[(size_t)(j + jj)*C_ + h*64 + e] = (bf16_t)acc[m][n][jj];
    }
  }
}

// ---------------------------------------------------------------- launcher
extern "C" void kernel_launch(void* const* d_in, const int* in_sizes, int n_in,
                              void* d_out, int out_size, void* d_ws, size_t ws_size,
                              hipStream_t stream)
{
  (void)in_sizes; (void)n_in; (void)out_size;
  const float* x     = (const float*)d_in[0];
  const float* w_qkv = (const float*)d_in[1];
  const float* b_qkv = (const float*)d_in[2];
  const float* w_out = (const float*)d_in[3];
  const float* b_out = (const float*)d_in[4];
  float* out = (float*)d_out;

  const size_t sz_xb   = (size_t)M_*C_*2;        // 50.3 MB
  const size_t sz_wq   = (size_t)TC_*C_*2;       //  3.5 MB
  const size_t sz_wo   = (size_t)C_*C_*2;        //  1.2 MB
  const size_t sz_qh   = (size_t)B_*H_*N_*D_*2;  // 50.3 MB
  const size_t sz_kv   = (size_t)B_*H_*D_*N_*2;  // 50.3 MB each
  const size_t sz_attn = (size_t)B_*H_*D_*D_*2;  //  3.1 MB

  char* p = (char*)d_ws;
  bf16_t* xb    = (bf16_t*)p; p += sz_xb;
  bf16_t* wqkvT = (bf16_t*)p; p += sz_wq;
  bf16_t* woutT = (bf16_t*)p; p += sz_wo;
  bf16_t* qh    = (bf16_t*)p; p += sz_qh;
  bf16_t* kthi  = (bf16_t*)p; p += sz_kv;
  bf16_t* vthi  = (bf16_t*)p; p += sz_kv;
  bf16_t* attnT = (bf16_t*)p; p += sz_attn;
  const size_t base_need = (size_t)(p - (char*)d_ws);
  // W' (32 x 768 x 768 bf16 = 37.7 MB) aliases xb (50.3 MB), dead after GEMM1
  bf16_t* w2t = xb;

  if (ws_size < base_need) return;   // leaves poison -> distinctive failure

  cvt_bf16<<<dim3((M_*C_)/2048), 256, 0, stream>>>(x, xb, M_*C_);
  transpose_cvt<<<dim3(TC_/32, C_/32), 256, 0, stream>>>(w_qkv, wqkvT, C_, TC_);
  transpose_cvt<<<dim3(C_/32,  C_/32), 256, 0, stream>>>(w_out, woutT, C_, C_);

  // GEMM1: qkv projection with scatter epilogue. grid = 18 x 256 = 4608
  gemm_bt<1><<<dim3((TC_/128)*(M_/128)), 256, 0, stream>>>(
      xb, wqkvT, b_qkv, nullptr, qh, kthi, vthi, C_, TC_/128, 0);

  attn_softmax_k<<<dim3(B_*H_), 256, 0, stream>>>(kthi, vthi, attnT);

  compose_w2<<<dim3(C_/128, B_*H_), 256, 0, stream>>>(woutT, attnT, w2t);

  // GEMM2: out = qh(gathered) @ W'_b + b_out. grid = 6 x 256 = 1536
  gemm_bt<3><<<dim3((C_/128)*(M_/128)), 256, 0, stream>>>(
      qh, w2t, b_out, out, nullptr, nullptr, nullptr, C_, C_/128, (size_t)C_*C_);
}

// Round 4
// 294.955 us; speedup vs baseline: 1.0665x; 1.0665x over previous
//
#include <hip/hip_runtime.h>
#include <hip/hip_bf16.h>
#include <stdint.h>
#include <stddef.h>

// Problem constants
#define B_ 32
#define N_ 1024
#define C_ 768
#define H_ 12
#define D_ 64
#define M_ (B_*N_)     // 32768 rows
#define TC_ (3*C_)     // 2304 qkv cols
#define NT_ 24         // K tiles: 768 / 32

typedef __bf16 bf16_t;
typedef __attribute__((ext_vector_type(8))) __bf16 bf16x8;
typedef __attribute__((ext_vector_type(4))) __bf16 bf16x4;
typedef __attribute__((ext_vector_type(4))) float  f32x4;

#define MFMA16(a,b,c) __builtin_amdgcn_mfma_f32_16x16x32_bf16(a,b,c,0,0,0)

__device__ __forceinline__ void lds_load16(const void* g, void* l) {
  __builtin_amdgcn_global_load_lds(
      (const __attribute__((address_space(1))) void*)g,
      (__attribute__((address_space(3))) void*)l, 16, 0, 0);
}

// ---------------------------------------------------------------- converts
__global__ void cvt_bf16(const float* __restrict__ in, bf16_t* __restrict__ out, int n) {
  int i = (blockIdx.x * 256 + threadIdx.x) * 8;
  if (i >= n) return;
  const float4 a = *(const float4*)(in + i);
  const float4 b = *(const float4*)(in + i + 4);
  bf16x8 r;
  r[0]=(bf16_t)a.x; r[1]=(bf16_t)a.y; r[2]=(bf16_t)a.z; r[3]=(bf16_t)a.w;
  r[4]=(bf16_t)b.x; r[5]=(bf16_t)b.y; r[6]=(bf16_t)b.z; r[7]=(bf16_t)b.w;
  *(bf16x8*)(out + i) = r;
}

// out[c][r] = bf16(in[r][c]); grid (Cc/32, R/32), 256 threads
__global__ void transpose_cvt(const float* __restrict__ in, bf16_t* __restrict__ out,
                              int R, int Cc) {
  __shared__ float t[32][33];
  const int c0 = blockIdx.x * 32, r0 = blockIdx.y * 32;
  const int tx = threadIdx.x & 31, ty = threadIdx.x >> 5;  // ty 0..7
  #pragma unroll
  for (int k = 0; k < 4; ++k)
    t[ty + k*8][tx] = in[(size_t)(r0 + ty + k*8)*Cc + c0 + tx];
  __syncthreads();
  #pragma unroll
  for (int k = 0; k < 4; ++k)
    out[(size_t)(c0 + ty + k*8)*R + r0 + tx] = (bf16_t)t[tx][ty + k*8];
}

// ---------------------------------------------------------------- GEMM 128x128, 16x16x32 MFMA
// 3-buffer LDS ring, prefetch depth 2, raw s_barrier + counted per-wave vmcnt.
// Per wave per K-tile: 4 global_load_lds (A h0, A h1, B h0, B h1).
// MODE 1: qkv projection; scatter epilogue (q -> (b,h,n,d); k,v -> (b,h,d,n))
// MODE 3: out projection; A = qh gathered as (b*1024+n, h*64+d); fp32 out + bias;
//         BT has per-batch stride bt_bstride. K = 768 for both modes.
template<int MODE>
__global__ __launch_bounds__(256, 2)
void gemm_bt(const bf16_t* __restrict__ A, const bf16_t* __restrict__ BT,
             const float* __restrict__ bias, float* __restrict__ Cout,
             bf16_t* __restrict__ qh,
             bf16_t* __restrict__ kthi, bf16_t* __restrict__ vthi,
             int nbx, size_t bt_bstride)
{
  // 3 ring buffers of 16 KB (A 8KB + B 8KB); epilogue tile unions over them.
  __shared__ __align__(16) char smem[49152];
  bf16_t* tile = (bf16_t*)smem;            // [128 cols][pitch 136 rows] (34 KB)

  const int nwg = gridDim.x;
  const int cpx = nwg >> 3;                       // nwg % 8 == 0
  const int bid = blockIdx.x;
  const int swz = (bid & 7) * cpx + (bid >> 3);   // bijective XCD chunking
  const int bx  = swz % nbx;
  const int by  = swz / nbx;

  const int tid  = threadIdx.x;
  const int wave = tid >> 6;
  const int lane = tid & 63;
  const int rowBase = by * 128;
  const int colBase = bx * 128;
  const int wr = (wave >> 1) * 64;
  const int wc = (wave &  1) * 64;
  const int fr = lane & 15;
  const int fo = (lane >> 4) * 8;
  const int r0t = tid >> 2;              // staging row within half-tile
  const int c0t = (tid & 3) * 8;         // staging col (elements)

  bf16_t* As[3]; bf16_t* Bs[3];
  #pragma unroll
  for (int i = 0; i < 3; ++i) {
    As[i] = (bf16_t*)(smem + i * 16384);
    Bs[i] = (bf16_t*)(smem + i * 16384 + 8192);
  }

  const bf16_t* Bp = BT + (MODE == 3 ? (size_t)(rowBase >> 10) * bt_bstride : 0)
                        + (size_t)(colBase + r0t) * 768 + c0t;
  const bf16_t* Ap;
  size_t a_half;
  if (MODE == 3) {
    const int gr = rowBase + r0t;
    Ap = A + (size_t)(gr >> 10) * (H_ * N_ * D_) + (size_t)(gr & (N_ - 1)) * D_ + c0t;
    a_half = (size_t)64 * D_;
  } else {
    Ap = A + (size_t)(rowBase + r0t) * 768 + c0t;
    a_half = (size_t)64 * 768;
  }

  f32x4 acc[4][4] = {{0.f,0.f,0.f,0.f}};

#define STAGE(bi, t) do {                                                     \
    const int k0_ = (t) * 32;                                                 \
    const bf16_t* a0_ = (MODE == 3)                                           \
        ? Ap + (size_t)(k0_ >> 6) * (N_ * D_) + (k0_ & 63)                    \
        : Ap + k0_;                                                           \
    lds_load16(a0_,                 As[bi] + wave * 512);                     \
    lds_load16(a0_ + a_half,        As[bi] + 2048 + wave * 512);              \
    lds_load16(Bp + k0_,            Bs[bi] + wave * 512);                     \
    lds_load16(Bp + (size_t)64*768 + k0_, Bs[bi] + 2048 + wave * 512);        \
  } while (0)

#define COMPUTE(bi) do {                                                      \
    bf16x8 af_[4], bf_[4];                                                    \
    _Pragma("unroll")                                                         \
    for (int m = 0; m < 4; ++m)                                               \
      af_[m] = *(const bf16x8*)&As[bi][(wr + m*16 + fr)*32 + fo];             \
    _Pragma("unroll")                                                         \
    for (int n = 0; n < 4; ++n)                                               \
      bf_[n] = *(const bf16x8*)&Bs[bi][(wc + n*16 + fr)*32 + fo];             \
    _Pragma("unroll")                                                         \
    for (int m = 0; m < 4; ++m)                                               \
      _Pragma("unroll")                                                       \
      for (int n = 0; n < 4; ++n)                                             \
        acc[m][n] = MFMA16(af_[m], bf_[n], acc[m][n]);                        \
  } while (0)

#define WAITV(nn) do {                                                        \
    asm volatile("s_waitcnt vmcnt(" #nn ")" ::: "memory");                    \
    __builtin_amdgcn_sched_barrier(0);                                        \
    __builtin_amdgcn_s_barrier();                                             \
    __builtin_amdgcn_sched_barrier(0);                                        \
  } while (0)

#define ENDB() do {                                                           \
    asm volatile("s_waitcnt lgkmcnt(0)" ::: "memory");                        \
    __builtin_amdgcn_sched_barrier(0);                                        \
    __builtin_amdgcn_s_barrier();                                             \
    __builtin_amdgcn_sched_barrier(0);                                        \
  } while (0)

  // prologue: tiles 0,1 -> buffers 0,1
  STAGE(0, 0);
  STAGE(1, 1);

  int t = 0;
  #pragma unroll 1
  for (int it = 0; it < 7; ++it) {   // t = 0..20
    STAGE(2, t+2); WAITV(8); COMPUTE(0); ENDB();
    STAGE(0, t+3); WAITV(8); COMPUTE(1); ENDB();
    STAGE(1, t+4); WAITV(8); COMPUTE(2); ENDB();
    t += 3;
  }
  // t = 21: stage last tile (23) -> buf2
  STAGE(2, 23); WAITV(8); COMPUTE(0); ENDB();
  // t = 22: outstanding {22,23} -> wait tile 22 (oldest 4)
  WAITV(4); COMPUTE(1); ENDB();
  // t = 23: drain
  WAITV(0); COMPUTE(2); ENDB();

#undef STAGE
#undef COMPUTE
#undef WAITV
#undef ENDB

  if (MODE == 3) {
    #pragma unroll
    for (int n = 0; n < 4; ++n) {
      const int gc = colBase + wc + n*16 + fr;
      const float bb = bias[gc];
      #pragma unroll
      for (int m = 0; m < 4; ++m) {
        const int gr = rowBase + wr + m*16 + ((lane >> 4) << 2);
        #pragma unroll
        for (int j = 0; j < 4; ++j)
          Cout[(size_t)(gr + j)*C_ + gc] = acc[m][n][j] + bb;
      }
    }
  } else {
    // ---- stage fragments (bias added, bf16) into transposed LDS tile ----
    #pragma unroll
    for (int n = 0; n < 4; ++n) {
      const int c  = wc + n*16 + fr;
      const float bb = bias[colBase + c];
      #pragma unroll
      for (int m = 0; m < 4; ++m) {
        const int r0 = wr + m*16 + ((lane >> 4) << 2);
        bf16x4 hv;
        hv[0]=(bf16_t)(acc[m][0+n][0]+bb); // placeholder to keep structure clear
        hv[0]=(bf16_t)(acc[m][n][0]+bb); hv[1]=(bf16_t)(acc[m][n][1]+bb);
        hv[2]=(bf16_t)(acc[m][n][2]+bb); hv[3]=(bf16_t)(acc[m][n][3]+bb);
        *(bf16x4*)&tile[c*136 + r0] = hv;
      }
    }
    __syncthreads();
    const int s   = colBase / C_;          // 0=q 1=k 2=v (uniform per block)
    const int b   = rowBase >> 10;
    const int nn0 = rowBase & (N_ - 1);
    if (s == 0) {
      // q: row-major (b,h,n,d). thread t: row r=t>>1, head-half ch=t&1.
      const int r  = tid >> 1, ch = tid & 1;
      const int h  = (colBase >> 6) + ch;
      bf16_t* dst = qh + (((size_t)b*H_ + h)*N_ + nn0 + r)*D_;
      #pragma unroll
      for (int i0 = 0; i0 < 64; i0 += 8) {
        bf16x8 vv;
        #pragma unroll
        for (int i = 0; i < 8; ++i) vv[i] = tile[(ch*64 + i0 + i)*136 + r];
        *(bf16x8*)&dst[i0] = vv;
      }
    } else {
      // k/v: transposed (b,h,d,n). thread t: col c=t>>1, row-half rh=t&1.
      const int c  = tid >> 1, rh = tid & 1;
      const int rem = colBase + c - s*C_;
      const int h = rem >> 6, d = rem & 63;
      bf16_t* dst = (s == 1 ? kthi : vthi)
                    + (((size_t)b*H_ + h)*D_ + d)*N_ + nn0 + rh*64;
      #pragma unroll
      for (int i0 = 0; i0 < 64; i0 += 8)
        *(bf16x8*)&dst[i0] = *(const bf16x8*)&tile[c*136 + rh*64 + i0];
    }
  }
}

// ---------------------------------------------------------------- stage 2: logits + softmax
// attnT[bh][e][d] = P[d][e], P = softmax_e( sum_n kt[d][n]*vt[e][n] / 8 )
__global__ __launch_bounds__(256, 2)
void attn_softmax_k(const bf16_t* __restrict__ kthi, const bf16_t* __restrict__ vthi,
                    bf16_t* __restrict__ attnT)
{
  __shared__ float tile[64][65];
  __shared__ float invs[64];
  const int bh = blockIdx.x;
  const int tid = threadIdx.x, wave = tid >> 6, lane = tid & 63;
  const int fr = lane & 15, fo = (lane >> 4) * 8;
  const size_t base = (size_t)bh * D_ * N_;
  f32x4 acc[4][4] = {{0.f,0.f,0.f,0.f}};
  const int k0lo = wave * 256;   // split-K across 4 waves
  #pragma unroll 1
  for (int k0 = k0lo; k0 < k0lo + 256; k0 += 32) {
    bf16x8 ah[4], bhv[4];
    #pragma unroll
    for (int m = 0; m < 4; ++m)
      ah[m] = *(const bf16x8*)&kthi[base + (size_t)(m*16 + fr)*N_ + k0 + fo];
    #pragma unroll
    for (int n = 0; n < 4; ++n)
      bhv[n] = *(const bf16x8*)&vthi[base + (size_t)(n*16 + fr)*N_ + k0 + fo];
    #pragma unroll
    for (int m = 0; m < 4; ++m)
      #pragma unroll
      for (int n = 0; n < 4; ++n)
        acc[m][n] = MFMA16(ah[m], bhv[n], acc[m][n]);
  }
  // cross-wave reduce into LDS
  for (int w = 0; w < 4; ++w) {
    if (wave == w) {
      #pragma unroll
      for (int m = 0; m < 4; ++m)
        #pragma unroll
        for (int n = 0; n < 4; ++n) {
          const int row = m*16 + ((lane >> 4) << 2);
          const int col = n*16 + fr;
          #pragma unroll
          for (int j = 0; j < 4; ++j) {
            if (w == 0) tile[row+j][col]  = acc[m][n][j];
            else        tile[row+j][col] += acc[m][n][j];
          }
        }
    }
    __syncthreads();
  }
  // row softmax (scale 1/8), one thread per row d
  if (tid < 64) {
    float mx = -3.0e38f;
    #pragma unroll
    for (int c = 0; c < 64; ++c) mx = fmaxf(mx, tile[tid][c]);
    mx *= 0.125f;
    float ssum = 0.f;
    #pragma unroll
    for (int c = 0; c < 64; ++c) {
      const float ev = __expf(tile[tid][c]*0.125f - mx);
      tile[tid][c] = ev;
      ssum += ev;
    }
    invs[tid] = 1.0f / ssum;
  }
  __syncthreads();
  // transposed write: thread e writes attnT[e][0..63] contiguous
  if (tid < 64) {
    bf16_t* ao = attnT + (size_t)bh * D_ * D_ + tid * D_;
    #pragma unroll
    for (int d0 = 0; d0 < 64; d0 += 8) {
      bf16x8 vv;
      #pragma unroll
      for (int i = 0; i < 8; ++i) vv[i] = (bf16_t)(tile[d0+i][tid] * invs[d0+i]);
      *(bf16x8*)&ao[d0] = vv;
    }
  }
}

// ---------------------------------------------------------------- stage 3: W' compose
// w2t[b][j][h*64+e] = sum_d woutT[j][h*64+d] * attnT[bh][e][d]
// grid (6, B*H), 256 threads (4 waves x 32 j-rows each)
__global__ __launch_bounds__(256, 2)
void compose_w2(const bf16_t* __restrict__ woutT, const bf16_t* __restrict__ attnT,
                bf16_t* __restrict__ w2t)
{
  const int jb = blockIdx.x;
  const int bh = blockIdx.y;
  const int b = bh / H_, h = bh - b*H_;
  const int tid = threadIdx.x, wave = tid >> 6, lane = tid & 63;
  const int fr = lane & 15, fo = (lane >> 4) * 8;
  const bf16_t* at = attnT + (size_t)bh * D_ * D_;
  f32x4 acc[2][4] = {{0.f,0.f,0.f,0.f}};
  #pragma unroll
  for (int kk = 0; kk < 2; ++kk) {
    bf16x8 af[2], bfv[4];
    #pragma unroll
    for (int m = 0; m < 2; ++m)
      af[m] = *(const bf16x8*)&woutT[(size_t)(jb*128 + wave*32 + m*16 + fr)*C_ + h*64 + kk*32 + fo];
    #pragma unroll
    for (int n = 0; n < 4; ++n)
      bfv[n] = *(const bf16x8*)&at[(n*16 + fr)*64 + kk*32 + fo];
    #pragma unroll
    for (int m = 0; m < 2; ++m)
      #pragma unroll
      for (int n = 0; n < 4; ++n)
        acc[m][n] = MFMA16(af[m], bfv[n], acc[m][n]);
  }
  bf16_t* wb = w2t + (size_t)b * C_ * C_;
  #pragma unroll
  for (int m = 0; m < 2; ++m) {
    const int j = jb*128 + wave*32 + m*16 + ((lane >> 4) << 2);
    #pragma unroll
    for (int n = 0; n < 4; ++n) {
      const int e = n*16 + fr;
      #pragma unroll
      for (int jj = 0; jj < 4; ++jj)
        wb[(size_t)(j + jj)*C_ + h*64 + e] = (bf16_t)acc[m][n][jj];
    }
  }
}

// ---------------------------------------------------------------- launcher
extern "C" void kernel_launch(void* const* d_in, const int* in_sizes, int n_in,
                              void* d_out, int out_size, void* d_ws, size_t ws_size,
                              hipStream_t stream)
{
  (void)in_sizes; (void)n_in; (void)out_size;
  const float* x     = (const float*)d_in[0];
  const float* w_qkv = (const float*)d_in[1];
  const float* b_qkv = (const float*)d_in[2];
  const float* w_out = (const float*)d_in[3];
  const float* b_out = (const float*)d_in[4];
  float* out = (float*)d_out;

  const size_t sz_xb   = (size_t)M_*C_*2;        // 50.3 MB
  const size_t sz_wq   = (size_t)TC_*C_*2;       //  3.5 MB
  const size_t sz_wo   = (size_t)C_*C_*2;        //  1.2 MB
  const size_t sz_qh   = (size_t)B_*H_*N_*D_*2;  // 50.3 MB
  const size_t sz_kv   = (size_t)B_*H_*D_*N_*2;  // 50.3 MB each
  const size_t sz_attn = (size_t)B_*H_*D_*D_*2;  //  3.1 MB

  char* p = (char*)d_ws;
  bf16_t* xb    = (bf16_t*)p; p += sz_xb;
  bf16_t* wqkvT = (bf16_t*)p; p += sz_wq;
  bf16_t* woutT = (bf16_t*)p; p += sz_wo;
  bf16_t* qh    = (bf16_t*)p; p += sz_qh;
  bf16_t* kthi  = (bf16_t*)p; p += sz_kv;
  bf16_t* vthi  = (bf16_t*)p; p += sz_kv;
  bf16_t* attnT = (bf16_t*)p; p += sz_attn;
  const size_t base_need = (size_t)(p - (char*)d_ws);
  // W' (32 x 768 x 768 bf16 = 37.7 MB) aliases xb (50.3 MB), dead after GEMM1
  bf16_t* w2t = xb;

  if (ws_size < base_need) return;   // leaves poison -> distinctive failure

  cvt_bf16<<<dim3((M_*C_)/2048), 256, 0, stream>>>(x, xb, M_*C_);
  transpose_cvt<<<dim3(TC_/32, C_/32), 256, 0, stream>>>(w_qkv, wqkvT, C_, TC_);
  transpose_cvt<<<dim3(C_/32,  C_/32), 256, 0, stream>>>(w_out, woutT, C_, C_);

  // GEMM1: qkv projection with scatter epilogue. grid = 18 x 256 = 4608
  gemm_bt<1><<<dim3((TC_/128)*(M_/128)), 256, 0, stream>>>(
      xb, wqkvT, b_qkv, nullptr, qh, kthi, vthi, TC_/128, 0);

  attn_softmax_k<<<dim3(B_*H_), 256, 0, stream>>>(kthi, vthi, attnT);

  compose_w2<<<dim3(C_/128, B_*H_), 256, 0, stream>>>(woutT, attnT, w2t);

  // GEMM2: out = qh(gathered) @ W'_b + b_out. grid = 6 x 256 = 1536
  gemm_bt<3><<<dim3((C_/128)*(M_/128)), 256, 0, stream>>>(
      qh, w2t, b_out, out, nullptr, nullptr, nullptr, C_/128, (size_t)C_*C_);
}